// Round 1
// baseline (513.110 us; speedup 1.0000x reference)
//
#include <hip/hip_runtime.h>
#include <math.h>

namespace {
constexpr int B_ = 4, S_ = 4096, D_ = 2048;
constexpr int RS_ = 6, RF_ = 21;
constexpr int CHUNK = 128, NCH = S_ / CHUNK;   // 32 chunks per sequence
constexpr int G_ = 8;                          // rows per block in k_main
constexpr float EPS_ = 1e-6f;

__device__ __forceinline__ float wred(float v) {
  v += __shfl_down(v, 32);
  v += __shfl_down(v, 16);
  v += __shfl_down(v, 8);
  v += __shfl_down(v, 4);
  v += __shfl_down(v, 2);
  v += __shfl_down(v, 1);
  return v;
}

__device__ __forceinline__ float gelu_tanh(float x) {
  float x3 = x * x * x;
  float inner = 0.7978845608028654f * (x + 0.044715f * x3);
  return 0.5f * x * (1.0f + tanhf(inner));
}
} // namespace

// ---------------- K0: transpose W1 -> [RF][D], U -> [RS][D] ----------------
extern "C" __global__ void k_transpose(const float* __restrict__ W1,
                                       const float* __restrict__ U,
                                       float* __restrict__ w1t,
                                       float* __restrict__ ut) {
  int t = blockIdx.x * 256 + threadIdx.x;
  if (t < D_ * RF_) {
    int d = t % D_, j = t / D_;
    w1t[t] = W1[d * RF_ + j];
  } else {
    int t2 = t - D_ * RF_;
    if (t2 < D_ * RS_) {
      int d = t2 % D_, r = t2 / D_;
      ut[t2] = U[d * RS_ + r];
    }
  }
}

// ---------------- K1: per-row RMS stat + u = rmsnorm(x)@U ----------------
extern "C" __global__ __launch_bounds__(256) void k_uproj(
    const float* __restrict__ x, const float* __restrict__ n1w,
    const float* __restrict__ ut, float* __restrict__ u_out) {
  int row = blockIdx.x;
  int tid = threadIdx.x;
  int lane = tid & 63, wv = tid >> 6;
  const float* xr = x + (size_t)row * D_;
  int c0 = tid * 4, c1 = 1024 + tid * 4;
  float4 xa = *(const float4*)(xr + c0);
  float4 xb = *(const float4*)(xr + c1);
  float4 wa = *(const float4*)(n1w + c0);
  float4 wb = *(const float4*)(n1w + c1);
  float xs[8] = {xa.x, xa.y, xa.z, xa.w, xb.x, xb.y, xb.z, xb.w};
  float wx[8] = {xa.x * wa.x, xa.y * wa.y, xa.z * wa.z, xa.w * wa.w,
                 xb.x * wb.x, xb.y * wb.y, xb.z * wb.z, xb.w * wb.w};
  float vals[7];
  float s2 = 0.f;
#pragma unroll
  for (int k = 0; k < 8; ++k) s2 = fmaf(xs[k], xs[k], s2);
  vals[6] = s2;
#pragma unroll
  for (int r = 0; r < RS_; ++r) {
    const float* utr = ut + r * D_;
    float4 ua = *(const float4*)(utr + c0);
    float4 ub = *(const float4*)(utr + c1);
    float uu[8] = {ua.x, ua.y, ua.z, ua.w, ub.x, ub.y, ub.z, ub.w};
    float p = 0.f;
#pragma unroll
    for (int k = 0; k < 8; ++k) p = fmaf(wx[k], uu[k], p);
    vals[r] = p;
  }
  __shared__ float red[7][4];
  __shared__ float tot[7];
#pragma unroll
  for (int i = 0; i < 7; ++i) {
    float v = wred(vals[i]);
    if (lane == 0) red[i][wv] = v;
  }
  __syncthreads();
  if (tid < 7) tot[tid] = red[tid][0] + red[tid][1] + red[tid][2] + red[tid][3];
  __syncthreads();
  if (tid < RS_) {
    float rinv = rsqrtf(tot[6] * (1.0f / D_) + EPS_);
    u_out[(size_t)row * RS_ + tid] = tot[tid] * rinv;
  }
}

// ---------------- K2: chunked parallel scan over S ----------------
// grid = B*RS blocks, 32 threads (one per chunk of 128).
// Writes local scans to hs, exclusive chunk carries to carryex, a^k table.
extern "C" __global__ __launch_bounds__(32) void k_scan(
    const float* __restrict__ lam, const float* __restrict__ u,
    float* __restrict__ hs, float* __restrict__ carryex,
    float* __restrict__ apow) {
  int b = blockIdx.x / RS_, r = blockIdx.x % RS_;
  int ch = threadIdx.x;
  float a = 1.0f / (1.0f + expf(-lam[r]));
  if (b == 0) {
    for (int k = ch; k <= CHUNK; k += 32) apow[r * (CHUNK + 1) + k] = powf(a, (float)k);
  }
  float h = 0.f;
  int base = (b * S_ + ch * CHUNK) * RS_ + r;
  for (int i = 0; i < CHUNK; ++i) {
    h = fmaf(a, h, u[base + i * RS_]);
    hs[base + i * RS_] = h;
  }
  __shared__ float carr[32];
  carr[ch] = h;
  __syncthreads();
  if (ch == 0) {
    float a128 = powf(a, 128.0f);
    float c = 0.f;
    int cb = (b * RS_ + r) * NCH;
    for (int q = 0; q < NCH; ++q) {
      carryex[cb + q] = c;
      c = fmaf(a128, c, carr[q]);
    }
  }
}

// ---------------- K3: fused y-proj + residual + rmsnorm2 + FFN + residual ----
extern "C" __global__ __launch_bounds__(256, 2) void k_main(
    const float* __restrict__ x, const float* __restrict__ V,
    const float* __restrict__ n2w, const float* __restrict__ w1t,
    const float* __restrict__ W2, const float* __restrict__ hsv,
    const float* __restrict__ carryex, const float* __restrict__ apow,
    float* __restrict__ out) {
  __shared__ float shs[G_][RS_];
  __shared__ float spT[4][G_][RF_];
  __shared__ float sg[G_][RF_];
  __shared__ float srinv[G_];
  __shared__ float red[G_][4];

  int tid = threadIdx.x;
  int lane = tid & 63, wv = tid >> 6;
  size_t base_row = (size_t)blockIdx.x * G_;
  int b = (int)(base_row / S_);
  int s0 = (int)(base_row % S_);
  int chunk = s0 >> 7;  // all G_ rows in same chunk (s0 % 8 == 0, G_=8 <= 128)

  // phase a: finalize scan values for this block's rows
  if (tid < G_ * RS_) {
    int g = tid / RS_, r = tid - g * RS_;
    int sl = (s0 + g) & (CHUNK - 1);
    shs[g][r] = hsv[(base_row + g) * RS_ + r] +
                apow[r * (CHUNK + 1) + sl + 1] * carryex[(b * RS_ + r) * NCH + chunk];
  }
  __syncthreads();

  int c0 = tid * 4, c1 = 1024 + tid * 4;

  // phase b: x2 = x + hs @ V (kept in registers), per-row sum of squares
  float vr[RS_][8];
#pragma unroll
  for (int r = 0; r < RS_; ++r) {
    float4 va = *(const float4*)(V + r * D_ + c0);
    float4 vb = *(const float4*)(V + r * D_ + c1);
    vr[r][0] = va.x; vr[r][1] = va.y; vr[r][2] = va.z; vr[r][3] = va.w;
    vr[r][4] = vb.x; vr[r][5] = vb.y; vr[r][6] = vb.z; vr[r][7] = vb.w;
  }
  float x2[G_][8];
  float ssq[G_];
#pragma unroll
  for (int g = 0; g < G_; ++g) {
    const float* xr = x + (base_row + g) * D_;
    float4 xa = *(const float4*)(xr + c0);
    float4 xb = *(const float4*)(xr + c1);
    float e[8] = {xa.x, xa.y, xa.z, xa.w, xb.x, xb.y, xb.z, xb.w};
#pragma unroll
    for (int r = 0; r < RS_; ++r) {
      float h = shs[g][r];
#pragma unroll
      for (int k = 0; k < 8; ++k) e[k] = fmaf(h, vr[r][k], e[k]);
    }
    float s2 = 0.f;
#pragma unroll
    for (int k = 0; k < 8; ++k) {
      x2[g][k] = e[k];
      s2 = fmaf(e[k], e[k], s2);
    }
    ssq[g] = s2;
  }
#pragma unroll
  for (int g = 0; g < G_; ++g) {
    float v = wred(ssq[g]);
    if (lane == 0) red[g][wv] = v;
  }
  __syncthreads();
  if (tid < G_) {
    srinv[tid] =
        rsqrtf((red[tid][0] + red[tid][1] + red[tid][2] + red[tid][3]) * (1.0f / D_) + EPS_);
  }
  __syncthreads();

  // phase c: T[g][j] = rinv_g * sum_d x2[g][d] * (n2w[d] * W1[d][j])
  float4 wna = *(const float4*)(n2w + c0);
  float4 wnb = *(const float4*)(n2w + c1);
  float wn[8] = {wna.x, wna.y, wna.z, wna.w, wnb.x, wnb.y, wnb.z, wnb.w};
  for (int j = 0; j < RF_; ++j) {
    float4 qa = *(const float4*)(w1t + j * D_ + c0);
    float4 qb = *(const float4*)(w1t + j * D_ + c1);
    float q[8] = {qa.x, qa.y, qa.z, qa.w, qb.x, qb.y, qb.z, qb.w};
#pragma unroll
    for (int k = 0; k < 8; ++k) q[k] *= wn[k];
#pragma unroll
    for (int g = 0; g < G_; ++g) {
      float p = 0.f;
#pragma unroll
      for (int k = 0; k < 8; ++k) p = fmaf(x2[g][k], q[k], p);
      p = wred(p);
      if (lane == 0) spT[wv][g][j] = p;
    }
  }
  __syncthreads();
  if (tid < G_ * RF_) {
    int g = tid / RF_, j = tid - g * RF_;
    float T = (spT[0][g][j] + spT[1][g][j] + spT[2][g][j] + spT[3][g][j]) * srinv[g];
    sg[g][j] = gelu_tanh(T);
  }
  __syncthreads();

  // phase d: out = x2 + gelu(T) @ W2 (accumulate into x2 registers)
  for (int j = 0; j < RF_; ++j) {
    float4 ra = *(const float4*)(W2 + j * D_ + c0);
    float4 rb = *(const float4*)(W2 + j * D_ + c1);
    float w2r[8] = {ra.x, ra.y, ra.z, ra.w, rb.x, rb.y, rb.z, rb.w};
#pragma unroll
    for (int g = 0; g < G_; ++g) {
      float gj = sg[g][j];
#pragma unroll
      for (int k = 0; k < 8; ++k) x2[g][k] = fmaf(gj, w2r[k], x2[g][k]);
    }
  }
#pragma unroll
  for (int g = 0; g < G_; ++g) {
    float* outr = out + (base_row + g) * D_;
    *(float4*)(outr + c0) = make_float4(x2[g][0], x2[g][1], x2[g][2], x2[g][3]);
    *(float4*)(outr + c1) = make_float4(x2[g][4], x2[g][5], x2[g][6], x2[g][7]);
  }
}

extern "C" void kernel_launch(void* const* d_in, const int* in_sizes, int n_in,
                              void* d_out, int out_size, void* d_ws, size_t ws_size,
                              hipStream_t stream) {
  const float* x   = (const float*)d_in[0];
  const float* n1w = (const float*)d_in[1];
  const float* U   = (const float*)d_in[2];
  const float* lam = (const float*)d_in[3];
  const float* V   = (const float*)d_in[4];
  const float* n2w = (const float*)d_in[5];
  const float* W1  = (const float*)d_in[6];
  const float* W2  = (const float*)d_in[7];
  float* out = (float*)d_out;
  float* ws  = (float*)d_ws;

  // ws layout (floats): u[98304] | hs[98304] | carryex[768] | apow[776] | w1t[43008] | ut[12288]
  float* u_ws    = ws;
  float* hs_ws   = ws + 98304;
  float* carry_ws= ws + 196608;
  float* apow_ws = ws + 197376;
  float* w1t_ws  = ws + 198152;
  float* ut_ws   = ws + 241160;

  k_transpose<<<216, 256, 0, stream>>>(W1, U, w1t_ws, ut_ws);
  k_uproj<<<B_ * S_, 256, 0, stream>>>(x, n1w, ut_ws, u_ws);
  k_scan<<<B_ * RS_, 32, 0, stream>>>(lam, u_ws, hs_ws, carry_ws, apow_ws);
  k_main<<<(B_ * S_) / G_, 256, 0, stream>>>(x, V, n2w, w1t_ws, W2, hs_ws, carry_ws,
                                             apow_ws, out);
}

// Round 3
// 414.756 us; speedup vs baseline: 1.2371x; 1.2371x over previous
//
#include <hip/hip_runtime.h>
#include <math.h>

namespace {
constexpr int S_ = 4096, D_ = 2048;
constexpr int RS_ = 6, RF_ = 21;
constexpr float EPS_ = 1e-6f;

// ---- DPP 64-lane sum reduction (rocPRIM pattern), result broadcast via readlane ----
#define DPP_ADD_(v, ctrl) \
  v += __int_as_float(__builtin_amdgcn_update_dpp(0, __float_as_int(v), ctrl, 0xF, 0xF, true))

__device__ __forceinline__ float wave_sum(float v) {
  DPP_ADD_(v, 0x111);  // row_shr:1
  DPP_ADD_(v, 0x112);  // row_shr:2
  DPP_ADD_(v, 0x114);  // row_shr:4
  DPP_ADD_(v, 0x118);  // row_shr:8  -> lane15 of each row16 = row sum
  DPP_ADD_(v, 0x142);  // row_bcast:15 -> lane31 = rows0+1, lane63 = rows2+3
  DPP_ADD_(v, 0x143);  // row_bcast:31 -> lane63 = total
  return __int_as_float(__builtin_amdgcn_readlane(__float_as_int(v), 63));
}

__device__ __forceinline__ float rdlane(float v, int l) {
  return __int_as_float(__builtin_amdgcn_readlane(__float_as_int(v), l));
}

// "write" a wave-uniform value into one lane of a register: predicated move.
__device__ __forceinline__ float sel_lane(float old, float val, int tgt, int lane) {
  return (lane == tgt) ? val : old;
}

__device__ __forceinline__ float gelu_f(float x) {
  // gelu_tanh(x) == x * sigmoid(2 * 0.7978845608*(x + 0.044715 x^3))
  float i2 = 1.5957691216057308f * fmaf(0.044715f * x * x, x, x);
  return x * __builtin_amdgcn_rcpf(1.f + __expf(-i2));
}

__device__ __forceinline__ float dot4(float4 a, float4 b) {
  return fmaf(a.x, b.x, fmaf(a.y, b.y, fmaf(a.z, b.z, a.w * b.w)));
}
} // namespace

// ---------------- K0: prep — fold norm weights, transpose small mats ----------------
extern "C" __global__ void k_prep(const float* __restrict__ W1, const float* __restrict__ U,
                                  const float* __restrict__ n1w, const float* __restrict__ n2w,
                                  float* __restrict__ w1t, float* __restrict__ ut) {
  int t = blockIdx.x * 256 + threadIdx.x;
  if (t < D_ * RF_) {
    int d = t / RF_, j = t - d * RF_;
    w1t[j * D_ + d] = W1[t] * n2w[d];
  }
  int t2 = t - D_ * RF_;
  if (t2 >= 0 && t2 < D_ * RS_) {
    int d = t2 / RS_, r = t2 - d * RS_;
    ut[r * D_ + d] = U[t2] * n1w[d];
  }
}

// ---------------- K1: RMS1 + U-projection. Wave owns 8 rows, DPP reductions --------
extern "C" __global__ __launch_bounds__(256, 4) void k_rms1(
    const float* __restrict__ x, const float* __restrict__ ut,
    float* __restrict__ u_t) {
  int tid = threadIdx.x, lane = tid & 63, wid = tid >> 6;
  int row0 = (blockIdx.x * 4 + wid) * 8;
  int b = row0 >> 12;
  int sb = row0 & (S_ - 1);
  int d0 = lane * 4;

  float uacc = 0.f;  // lane w*6+r holds u[row0+w][r]
#pragma unroll
  for (int w = 0; w < 8; ++w) {
    const float* xr = x + (size_t)(row0 + w) * D_;
    float4 xv[8];
#pragma unroll
    for (int k = 0; k < 8; ++k) xv[k] = *(const float4*)(xr + k * 256 + d0);
    float s2 = 0.f;
#pragma unroll
    for (int k = 0; k < 8; ++k) s2 += dot4(xv[k], xv[k]);
    float p[RS_];
#pragma unroll
    for (int r = 0; r < RS_; ++r) {
      const float* ur = ut + r * D_ + d0;
      float pp = 0.f;
#pragma unroll
      for (int k = 0; k < 8; ++k) {
        float4 uu = *(const float4*)(ur + k * 256);
        pp += dot4(xv[k], uu);
      }
      p[r] = pp;
    }
    float rinv = rsqrtf(wave_sum(s2) * (1.0f / D_) + EPS_);
#pragma unroll
    for (int r = 0; r < RS_; ++r) {
      float urv = wave_sum(p[r]) * rinv;
      uacc = sel_lane(uacc, urv, w * RS_ + r, lane);
    }
  }
  if (lane < 8 * RS_) {
    int w = lane / RS_, r = lane - w * RS_;
    u_t[(b * RS_ + r) * S_ + sb + w] = uacc;
  }
}

// ---------------- K2: scan. 1 block of 64 per (b,r); 64 chunks x 64; affine prefix --
extern "C" __global__ __launch_bounds__(64) void k_scan(
    const float* __restrict__ lam, const float* __restrict__ u_t,
    float* __restrict__ hs_t) {
  int br = blockIdx.x;            // b*6+r
  int r = br % RS_;
  int lane = threadIdx.x;
  float a = 1.f / (1.f + __expf(-lam[r]));
  float a64 = a;
#pragma unroll
  for (int i = 0; i < 6; ++i) a64 *= a64;  // a^64

  const float* ub = u_t + (size_t)br * S_ + lane * 64;
  float vloc = 0.f;
#pragma unroll
  for (int i = 0; i < 16; ++i) {
    float4 uu = *(const float4*)(ub + i * 4);
    vloc = fmaf(a, vloc, uu.x);
    vloc = fmaf(a, vloc, uu.y);
    vloc = fmaf(a, vloc, uu.z);
    vloc = fmaf(a, vloc, uu.w);
  }
  // inclusive affine scan over lanes: (m,v) = composition h -> m*h + v
  float m = a64, v = vloc;
#pragma unroll
  for (int off = 1; off < 64; off <<= 1) {
    float mu = __shfl_up(m, off);
    float vu = __shfl_up(v, off);
    if (lane >= off) {
      v = fmaf(m, vu, v);
      m *= mu;
    }
  }
  float carry = __shfl_up(v, 1);
  if (lane == 0) carry = 0.f;

  float h = carry;
  float* hb = hs_t + (size_t)br * S_ + lane * 64;
#pragma unroll
  for (int i = 0; i < 16; ++i) {
    float4 uu = *(const float4*)(ub + i * 4);
    float4 o;
    h = fmaf(a, h, uu.x); o.x = h;
    h = fmaf(a, h, uu.y); o.y = h;
    h = fmaf(a, h, uu.z); o.z = h;
    h = fmaf(a, h, uu.w); o.w = h;
    *(float4*)(hb + i * 4) = o;
  }
}

// ---------------- K3: fused V-proj + residual + RMS2 + FFN + residual --------------
// Wave owns 4 rows; no LDS, no __syncthreads, DPP reductions only.
extern "C" __global__ __launch_bounds__(256, 2) void k_main(
    const float* __restrict__ x, const float* __restrict__ V,
    const float* __restrict__ w1t, const float* __restrict__ W2,
    const float* __restrict__ hs_t, float* __restrict__ out) {
  int tid = threadIdx.x, lane = tid & 63, wid = tid >> 6;
  int row0 = blockIdx.x * 16 + wid * 4;
  int b = row0 >> 12;
  int s0 = row0 & (S_ - 1);
  int d0 = lane * 4;

  // scan values for this wave's 4 rows: lane w*6+r loads h[row0+w][r]
  float hv = 0.f;
  if (lane < 4 * RS_) {
    int w = lane / RS_, r = lane - w * RS_;
    hv = hs_t[(b * RS_ + r) * S_ + s0 + w];
  }

  // phase b: x2 = x + hs @ V   (x2 in registers: 4 rows x 32 elems/lane)
  float4 xv[4][8];
  const float* xr = x + (size_t)row0 * D_;
#pragma unroll
  for (int w = 0; w < 4; ++w)
#pragma unroll
    for (int k = 0; k < 8; ++k)
      xv[w][k] = *(const float4*)(xr + w * D_ + k * 256 + d0);

#pragma unroll
  for (int r = 0; r < RS_; ++r) {
    float4 vv[8];
#pragma unroll
    for (int k = 0; k < 8; ++k) vv[k] = *(const float4*)(V + r * D_ + k * 256 + d0);
#pragma unroll
    for (int w = 0; w < 4; ++w) {
      float h = rdlane(hv, w * RS_ + r);
#pragma unroll
      for (int k = 0; k < 8; ++k) {
        xv[w][k].x = fmaf(h, vv[k].x, xv[w][k].x);
        xv[w][k].y = fmaf(h, vv[k].y, xv[w][k].y);
        xv[w][k].z = fmaf(h, vv[k].z, xv[w][k].z);
        xv[w][k].w = fmaf(h, vv[k].w, xv[w][k].w);
      }
    }
  }

  // rms2 per row
  float rinv[4];
#pragma unroll
  for (int w = 0; w < 4; ++w) {
    float s2 = 0.f;
#pragma unroll
    for (int k = 0; k < 8; ++k) s2 += dot4(xv[w][k], xv[w][k]);
    rinv[w] = rsqrtf(wave_sum(s2) * (1.0f / D_) + EPS_);
  }

  // phase c: T[w][j] = rinv_w * <x2[w], w1t[j]>; pack into gv[w] lane j
  float gv[4] = {0.f, 0.f, 0.f, 0.f};
  for (int j = 0; j < RF_; ++j) {
    const float* qb = w1t + j * D_ + d0;
    float4 q[8];
#pragma unroll
    for (int k = 0; k < 8; ++k) q[k] = *(const float4*)(qb + k * 256);
#pragma unroll
    for (int w = 0; w < 4; ++w) {
      float p = 0.f;
#pragma unroll
      for (int k = 0; k < 8; ++k) p += dot4(xv[w][k], q[k]);
      float t = wave_sum(p) * rinv[w];
      gv[w] = sel_lane(gv[w], t, j, lane);
    }
  }
#pragma unroll
  for (int w = 0; w < 4; ++w) gv[w] = gelu_f(gv[w]);  // vector gelu over 21 lanes

  // phase d: out = x2 + g @ W2
  for (int j = 0; j < RF_; ++j) {
    const float* rb = W2 + j * D_ + d0;
    float4 q[8];
#pragma unroll
    for (int k = 0; k < 8; ++k) q[k] = *(const float4*)(rb + k * 256);
#pragma unroll
    for (int w = 0; w < 4; ++w) {
      float g = rdlane(gv[w], j);
#pragma unroll
      for (int k = 0; k < 8; ++k) {
        xv[w][k].x = fmaf(g, q[k].x, xv[w][k].x);
        xv[w][k].y = fmaf(g, q[k].y, xv[w][k].y);
        xv[w][k].z = fmaf(g, q[k].z, xv[w][k].z);
        xv[w][k].w = fmaf(g, q[k].w, xv[w][k].w);
      }
    }
  }

  float* orow = out + (size_t)row0 * D_;
#pragma unroll
  for (int w = 0; w < 4; ++w)
#pragma unroll
    for (int k = 0; k < 8; ++k)
      *(float4*)(orow + w * D_ + k * 256 + d0) = xv[w][k];
}

extern "C" void kernel_launch(void* const* d_in, const int* in_sizes, int n_in,
                              void* d_out, int out_size, void* d_ws, size_t ws_size,
                              hipStream_t stream) {
  const float* x   = (const float*)d_in[0];
  const float* n1w = (const float*)d_in[1];
  const float* U   = (const float*)d_in[2];
  const float* lam = (const float*)d_in[3];
  const float* V   = (const float*)d_in[4];
  const float* n2w = (const float*)d_in[5];
  const float* W1  = (const float*)d_in[6];
  const float* W2  = (const float*)d_in[7];
  float* out = (float*)d_out;
  float* ws  = (float*)d_ws;

  // ws layout (floats): u_t[98304] | hs_t[98304] | w1t[43008] | ut[12288]
  float* u_t  = ws;
  float* hs_t = ws + 98304;
  float* w1t  = ws + 196608;
  float* ut   = ws + 239616;

  k_prep<<<216, 256, 0, stream>>>(W1, U, n1w, n2w, w1t, ut);
  k_rms1<<<512, 256, 0, stream>>>(x, ut, u_t);
  k_scan<<<24, 64, 0, stream>>>(lam, u_t, hs_t);
  k_main<<<1024, 256, 0, stream>>>(x, V, w1t, W2, hs_t, out);
}

// Round 4
// 338.758 us; speedup vs baseline: 1.5147x; 1.2243x over previous
//
#include <hip/hip_runtime.h>
#include <math.h>

namespace {
constexpr int S_ = 4096, D_ = 2048;
constexpr int RS_ = 6, RF_ = 21;
constexpr float EPS_ = 1e-6f;

// ---- DPP 64-lane sum reduction, result broadcast via readlane ----
#define DPP_ADD_(v, ctrl) \
  v += __int_as_float(__builtin_amdgcn_update_dpp(0, __float_as_int(v), ctrl, 0xF, 0xF, true))

__device__ __forceinline__ float wave_sum(float v) {
  DPP_ADD_(v, 0x111);  // row_shr:1
  DPP_ADD_(v, 0x112);  // row_shr:2
  DPP_ADD_(v, 0x114);  // row_shr:4
  DPP_ADD_(v, 0x118);  // row_shr:8
  DPP_ADD_(v, 0x142);  // row_bcast:15
  DPP_ADD_(v, 0x143);  // row_bcast:31
  return __int_as_float(__builtin_amdgcn_readlane(__float_as_int(v), 63));
}

__device__ __forceinline__ float rdlane(float v, int l) {
  return __int_as_float(__builtin_amdgcn_readlane(__float_as_int(v), l));
}

__device__ __forceinline__ float sel_lane(float old, float val, int tgt, int lane) {
  return (lane == tgt) ? val : old;
}

__device__ __forceinline__ float gelu_f(float x) {
  float i2 = 1.5957691216057308f * fmaf(0.044715f * x * x, x, x);
  return x * __builtin_amdgcn_rcpf(1.f + __expf(-i2));
}

__device__ __forceinline__ float dot4(float4 a, float4 b) {
  return fmaf(a.x, b.x, fmaf(a.y, b.y, fmaf(a.z, b.z, a.w * b.w)));
}

__device__ __forceinline__ float4 fma4(float s, float4 a, float4 c) {
  return make_float4(fmaf(s, a.x, c.x), fmaf(s, a.y, c.y), fmaf(s, a.z, c.z),
                     fmaf(s, a.w, c.w));
}

// load a half weight-row slice: 4 x float4 at p, p+256, p+512, p+768
__device__ __forceinline__ void ld4(float4 (&q)[4], const float* p) {
  q[0] = *(const float4*)(p);
  q[1] = *(const float4*)(p + 256);
  q[2] = *(const float4*)(p + 512);
  q[3] = *(const float4*)(p + 768);
}
} // namespace

// ---------------- K0: prep — fold norm weights, transpose small mats ----------------
extern "C" __global__ void k_prep(const float* __restrict__ W1, const float* __restrict__ U,
                                  const float* __restrict__ n1w, const float* __restrict__ n2w,
                                  float* __restrict__ w1t, float* __restrict__ ut) {
  int t = blockIdx.x * 256 + threadIdx.x;
  if (t < D_ * RF_) {
    int d = t / RF_, j = t - d * RF_;
    w1t[j * D_ + d] = W1[t] * n2w[d];
  }
  int t2 = t - D_ * RF_;
  if (t2 >= 0 && t2 < D_ * RS_) {
    int d = t2 / RS_, r = t2 - d * RS_;
    ut[r * D_ + d] = U[t2] * n1w[d];
  }
}

// ---------------- K1: RMS1 + U-projection. 2 rows/wave, 2048 blocks ----------------
extern "C" __global__ __launch_bounds__(256, 6) void k_rms1(
    const float* __restrict__ x, const float* __restrict__ ut,
    float* __restrict__ u_t) {
  int tid = threadIdx.x, lane = tid & 63, wid = tid >> 6;
  int row0 = blockIdx.x * 8 + wid * 2;   // 2 consecutive rows per wave
  int b = row0 >> 12;
  int sb = row0 & (S_ - 1);
  int d0 = lane * 4;
  const float* xr = x + (size_t)row0 * D_ + d0;
  const float* up = ut + d0;

  float s2a = 0.f, s2b = 0.f;
  float pa0 = 0.f, pa1 = 0.f, pa2 = 0.f, pa3 = 0.f, pa4 = 0.f, pa5 = 0.f;
  float pb0 = 0.f, pb1 = 0.f, pb2 = 0.f, pb3 = 0.f, pb4 = 0.f, pb5 = 0.f;
#pragma unroll
  for (int k = 0; k < 8; ++k) {
    float4 xa = *(const float4*)(xr + k * 256);
    float4 xb = *(const float4*)(xr + D_ + k * 256);
    s2a += dot4(xa, xa);
    s2b += dot4(xb, xb);
    float4 u0 = *(const float4*)(up + 0 * D_ + k * 256);
    pa0 += dot4(xa, u0); pb0 += dot4(xb, u0);
    float4 u1 = *(const float4*)(up + 1 * D_ + k * 256);
    pa1 += dot4(xa, u1); pb1 += dot4(xb, u1);
    float4 u2 = *(const float4*)(up + 2 * D_ + k * 256);
    pa2 += dot4(xa, u2); pb2 += dot4(xb, u2);
    float4 u3 = *(const float4*)(up + 3 * D_ + k * 256);
    pa3 += dot4(xa, u3); pb3 += dot4(xb, u3);
    float4 u4 = *(const float4*)(up + 4 * D_ + k * 256);
    pa4 += dot4(xa, u4); pb4 += dot4(xb, u4);
    float4 u5 = *(const float4*)(up + 5 * D_ + k * 256);
    pa5 += dot4(xa, u5); pb5 += dot4(xb, u5);
  }
  // 14 independent reduction chains (compiler interleaves the DPP ops)
  float ra = rsqrtf(wave_sum(s2a) * (1.0f / D_) + EPS_);
  float rb = rsqrtf(wave_sum(s2b) * (1.0f / D_) + EPS_);
  float va0 = wave_sum(pa0) * ra, vb0 = wave_sum(pb0) * rb;
  float va1 = wave_sum(pa1) * ra, vb1 = wave_sum(pb1) * rb;
  float va2 = wave_sum(pa2) * ra, vb2 = wave_sum(pb2) * rb;
  float va3 = wave_sum(pa3) * ra, vb3 = wave_sum(pb3) * rb;
  float va4 = wave_sum(pa4) * ra, vb4 = wave_sum(pb4) * rb;
  float va5 = wave_sum(pa5) * ra, vb5 = wave_sum(pb5) * rb;

  // pack: lane 2r+0 -> row a value r, lane 2r+1 -> row b value r
  float uv = 0.f;
  uv = sel_lane(uv, va0, 0, lane);  uv = sel_lane(uv, vb0, 1, lane);
  uv = sel_lane(uv, va1, 2, lane);  uv = sel_lane(uv, vb1, 3, lane);
  uv = sel_lane(uv, va2, 4, lane);  uv = sel_lane(uv, vb2, 5, lane);
  uv = sel_lane(uv, va3, 6, lane);  uv = sel_lane(uv, vb3, 7, lane);
  uv = sel_lane(uv, va4, 8, lane);  uv = sel_lane(uv, vb4, 9, lane);
  uv = sel_lane(uv, va5, 10, lane); uv = sel_lane(uv, vb5, 11, lane);
  if (lane < 2 * RS_) {
    int r = lane >> 1, w = lane & 1;
    u_t[((size_t)b * RS_ + r) * S_ + sb + w] = uv;
  }
}

// ---------------- K2: scan. 1 block of 64 per (b,r); affine prefix over chunks -----
extern "C" __global__ __launch_bounds__(64) void k_scan(
    const float* __restrict__ lam, const float* __restrict__ u_t,
    float* __restrict__ hs_t) {
  int br = blockIdx.x;            // b*6+r
  int r = br % RS_;
  int lane = threadIdx.x;
  float a = 1.f / (1.f + __expf(-lam[r]));
  float a64 = a;
#pragma unroll
  for (int i = 0; i < 6; ++i) a64 *= a64;  // a^64

  const float* ub = u_t + (size_t)br * S_ + lane * 64;
  float vloc = 0.f;
#pragma unroll
  for (int i = 0; i < 16; ++i) {
    float4 uu = *(const float4*)(ub + i * 4);
    vloc = fmaf(a, vloc, uu.x);
    vloc = fmaf(a, vloc, uu.y);
    vloc = fmaf(a, vloc, uu.z);
    vloc = fmaf(a, vloc, uu.w);
  }
  float m = a64, v = vloc;
#pragma unroll
  for (int off = 1; off < 64; off <<= 1) {
    float mu = __shfl_up(m, off);
    float vu = __shfl_up(v, off);
    if (lane >= off) {
      v = fmaf(m, vu, v);
      m *= mu;
    }
  }
  float carry = __shfl_up(v, 1);
  if (lane == 0) carry = 0.f;

  float h = carry;
  float* hb = hs_t + (size_t)br * S_ + lane * 64;
#pragma unroll
  for (int i = 0; i < 16; ++i) {
    float4 uu = *(const float4*)(ub + i * 4);
    float4 o;
    h = fmaf(a, h, uu.x); o.x = h;
    h = fmaf(a, h, uu.y); o.y = h;
    h = fmaf(a, h, uu.z); o.z = h;
    h = fmaf(a, h, uu.w); o.w = h;
    *(float4*)(hb + i * 4) = o;
  }
}

// ---------------- K3: fused V-proj + residual + RMS2 + FFN + residual --------------
// 4 rows/wave, explicit half-row software-pipelined weight stream, no LDS.
extern "C" __global__ __launch_bounds__(256, 2) void k_main(
    const float* __restrict__ x, const float* __restrict__ V,
    const float* __restrict__ w1t, const float* __restrict__ W2,
    const float* __restrict__ hs_t, float* __restrict__ out) {
  int tid = threadIdx.x, lane = tid & 63, wid = tid >> 6;
  int row0 = blockIdx.x * 16 + wid * 4;
  int b = row0 >> 12;
  int s0 = row0 & (S_ - 1);
  int d0 = lane * 4;

  // scan values: lane w*6+r holds h[row0+w][r]
  float hv = 0.f;
  if (lane < 4 * RS_) {
    int w = lane / RS_, r = lane - w * RS_;
    hv = hs_t[((size_t)b * RS_ + r) * S_ + s0 + w];
  }

  // issue the HBM x stream early (32 x float4)
  float4 xv[4][8];
  const float* xr = x + (size_t)row0 * D_ + d0;
#pragma unroll
  for (int w = 0; w < 4; ++w)
#pragma unroll
    for (int k = 0; k < 8; ++k)
      xv[w][k] = *(const float4*)(xr + w * D_ + k * 256);

  float4 qA[4], qB[4];

  // phase b: x2 = x + hs @ V   (half-row pipelined)
  const float* Vp = V + d0;
  ld4(qA, Vp);
#pragma unroll 2
  for (int r = 0; r < RS_; ++r) {
    ld4(qB, Vp + r * D_ + 1024);
    float h0 = rdlane(hv, 0 * RS_ + r), h1 = rdlane(hv, 1 * RS_ + r);
    float h2 = rdlane(hv, 2 * RS_ + r), h3 = rdlane(hv, 3 * RS_ + r);
#pragma unroll
    for (int k = 0; k < 4; ++k) {
      xv[0][k] = fma4(h0, qA[k], xv[0][k]);
      xv[1][k] = fma4(h1, qA[k], xv[1][k]);
      xv[2][k] = fma4(h2, qA[k], xv[2][k]);
      xv[3][k] = fma4(h3, qA[k], xv[3][k]);
    }
    if (r + 1 < RS_) ld4(qA, Vp + (r + 1) * D_);
#pragma unroll
    for (int k = 0; k < 4; ++k) {
      xv[0][4 + k] = fma4(h0, qB[k], xv[0][4 + k]);
      xv[1][4 + k] = fma4(h1, qB[k], xv[1][4 + k]);
      xv[2][4 + k] = fma4(h2, qB[k], xv[2][4 + k]);
      xv[3][4 + k] = fma4(h3, qB[k], xv[3][4 + k]);
    }
  }

  // rms2 per row
  float s20 = 0.f, s21 = 0.f, s22 = 0.f, s23 = 0.f;
#pragma unroll
  for (int k = 0; k < 8; ++k) {
    s20 += dot4(xv[0][k], xv[0][k]);
    s21 += dot4(xv[1][k], xv[1][k]);
    s22 += dot4(xv[2][k], xv[2][k]);
    s23 += dot4(xv[3][k], xv[3][k]);
  }
  float rinv0 = rsqrtf(wave_sum(s20) * (1.0f / D_) + EPS_);
  float rinv1 = rsqrtf(wave_sum(s21) * (1.0f / D_) + EPS_);
  float rinv2 = rsqrtf(wave_sum(s22) * (1.0f / D_) + EPS_);
  float rinv3 = rsqrtf(wave_sum(s23) * (1.0f / D_) + EPS_);

  // phase c: T[w][j] = rinv_w * <x2[w], w1t[j]>, packed into lane j of g_w
  float g0 = 0.f, g1 = 0.f, g2 = 0.f, g3 = 0.f;
  const float* Wp = w1t + d0;
  ld4(qA, Wp);
#pragma unroll 3
  for (int j = 0; j < RF_; ++j) {
    ld4(qB, Wp + j * D_ + 1024);
    float p0 = 0.f, p1 = 0.f, p2 = 0.f, p3 = 0.f;
#pragma unroll
    for (int k = 0; k < 4; ++k) {
      p0 += dot4(xv[0][k], qA[k]);
      p1 += dot4(xv[1][k], qA[k]);
      p2 += dot4(xv[2][k], qA[k]);
      p3 += dot4(xv[3][k], qA[k]);
    }
    if (j + 1 < RF_) ld4(qA, Wp + (j + 1) * D_);
#pragma unroll
    for (int k = 0; k < 4; ++k) {
      p0 += dot4(xv[0][4 + k], qB[k]);
      p1 += dot4(xv[1][4 + k], qB[k]);
      p2 += dot4(xv[2][4 + k], qB[k]);
      p3 += dot4(xv[3][4 + k], qB[k]);
    }
    float t0 = wave_sum(p0) * rinv0;
    float t1 = wave_sum(p1) * rinv1;
    float t2 = wave_sum(p2) * rinv2;
    float t3 = wave_sum(p3) * rinv3;
    g0 = sel_lane(g0, t0, j, lane);
    g1 = sel_lane(g1, t1, j, lane);
    g2 = sel_lane(g2, t2, j, lane);
    g3 = sel_lane(g3, t3, j, lane);
  }
  g0 = gelu_f(g0); g1 = gelu_f(g1); g2 = gelu_f(g2); g3 = gelu_f(g3);

  // phase d: out = x2 + g @ W2  (half-row pipelined)
  const float* W2p = W2 + d0;
  ld4(qA, W2p);
#pragma unroll 3
  for (int j = 0; j < RF_; ++j) {
    ld4(qB, W2p + j * D_ + 1024);
    float f0 = rdlane(g0, j), f1 = rdlane(g1, j);
    float f2 = rdlane(g2, j), f3 = rdlane(g3, j);
#pragma unroll
    for (int k = 0; k < 4; ++k) {
      xv[0][k] = fma4(f0, qA[k], xv[0][k]);
      xv[1][k] = fma4(f1, qA[k], xv[1][k]);
      xv[2][k] = fma4(f2, qA[k], xv[2][k]);
      xv[3][k] = fma4(f3, qA[k], xv[3][k]);
    }
    if (j + 1 < RF_) ld4(qA, W2p + (j + 1) * D_);
#pragma unroll
    for (int k = 0; k < 4; ++k) {
      xv[0][4 + k] = fma4(f0, qB[k], xv[0][4 + k]);
      xv[1][4 + k] = fma4(f1, qB[k], xv[1][4 + k]);
      xv[2][4 + k] = fma4(f2, qB[k], xv[2][4 + k]);
      xv[3][4 + k] = fma4(f3, qB[k], xv[3][4 + k]);
    }
  }

  float* orow = out + (size_t)row0 * D_ + d0;
#pragma unroll
  for (int w = 0; w < 4; ++w)
#pragma unroll
    for (int k = 0; k < 8; ++k)
      *(float4*)(orow + w * D_ + k * 256) = xv[w][k];
}

extern "C" void kernel_launch(void* const* d_in, const int* in_sizes, int n_in,
                              void* d_out, int out_size, void* d_ws, size_t ws_size,
                              hipStream_t stream) {
  const float* x   = (const float*)d_in[0];
  const float* n1w = (const float*)d_in[1];
  const float* U   = (const float*)d_in[2];
  const float* lam = (const float*)d_in[3];
  const float* V   = (const float*)d_in[4];
  const float* n2w = (const float*)d_in[5];
  const float* W1  = (const float*)d_in[6];
  const float* W2  = (const float*)d_in[7];
  float* out = (float*)d_out;
  float* ws  = (float*)d_ws;

  // ws layout (floats): u_t[98304] | hs_t[98304] | w1t[43008] | ut[12288]
  float* u_t  = ws;
  float* hs_t = ws + 98304;
  float* w1t  = ws + 196608;
  float* ut   = ws + 239616;

  k_prep<<<216, 256, 0, stream>>>(W1, U, n1w, n2w, w1t, ut);
  k_rms1<<<2048, 256, 0, stream>>>(x, ut, u_t);
  k_scan<<<24, 64, 0, stream>>>(lam, u_t, hs_t);
  k_main<<<1024, 256, 0, stream>>>(x, V, w1t, W2, hs_t, out);
}